// Round 1
// baseline (165.892 us; speedup 1.0000x reference)
//
#include <hip/hip_runtime.h>

#define NUM_ITERS 500
#define LR_F 0.001f
#define VPLANE 262144    // 4*64*1024 floats
// K=1 Krylov truncation: s = d0*v0, d0 = 500*LR/||v0||.
// R18 conv structure retained verbatim (session optimum): deep-staging (R19),
// ci-splits (R14), and row-splits (R15) all regressed. Do not re-attempt.
// This round (R20): pipeline de-marshalling.
//  - k_prep removed: weight addresses are wave-uniform (och readfirstlane'd,
//    ci loop-uniform) -> raw 9-float rows load via s_load; transpose (WF) and
//    tap-flip (WZ) done by indexing. Tables WI/WF/WZ deleted.
//  - Gam atomic -> 256 per-block partials (no pre-zero needed), reduced at
//    top of k_finalize_p.
//  - k_fsum removed: k_vnorm writes out-base = relu(sumQ)+sumBq; k_finalize_p
//    atomicAdds its conv partials into out (stream order guarantees base
//    present; out fully rewritten by k_vnorm each replay).

// ---- register-safe unpack helpers -------------------------------------------
__device__ __forceinline__ void ldrow8b(const float* __restrict__ rp, float f[8]) {
  float4 a = *(const float4*)(rp);
  float4 b = *(const float4*)(rp + 4);
  f[0] = a.x; f[1] = a.y; f[2] = a.z; f[3] = a.w;
  f[4] = b.x; f[5] = b.y; f[6] = b.z; f[7] = b.w;
}

__device__ __forceinline__ void stg_write(float* sd, float4 v) {
  float2 u = {v.x, v.y}, w = {v.z, v.w};
  *(float2*)sd = u;
  *(float2*)(sd + 2) = w;
}

// ---- raw weight loads (wave-uniform addresses -> scalar loads) --------------
// init: Wff[(och*64+ci)*9 + k], slot 9 = Wb[och*64+ci]
__device__ __forceinline__ void wldI(const float* __restrict__ Wff,
                                     const float* __restrict__ Wb,
                                     int oc, float w[12]) {
  const float* s = Wff + (size_t)oc * 9;
#pragma unroll
  for (int k = 0; k < 9; ++k) w[k] = s[k];
  w[9] = Wb[oc];
}
// forward (transposed): Wfb[(ci*64+och)*9 + k]
__device__ __forceinline__ void wldF(const float* __restrict__ Wfb,
                                     int ci, int och, float w[12]) {
  const float* s = Wfb + ((size_t)ci * 64 + och) * 9;
#pragma unroll
  for (int k = 0; k < 9; ++k) w[k] = s[k];
  w[9] = 0.f;
}
// finalize (tap-flipped): Wfb[(co*64+ci)*9 + (8-k)]
__device__ __forceinline__ void wldZ(const float* __restrict__ Wfb,
                                     int co, int ci, float w[12]) {
  const float* s = Wfb + ((size_t)co * 64 + ci) * 9;
#pragma unroll
  for (int k = 0; k < 9; ++k) w[k] = s[8 - k];
  w[9] = 0.f;
}

// ---- conv16_3: 3x3 pad1 over full-plane LDS (pitch 44, halo+2), 16 px -------
template <bool BYP>
__device__ __forceinline__ void conv16_3(const float* __restrict__ pb, const float w[12],
                                         int strip4, int cg4, float acc[16], float by[16]) {
  float wb = w[9];
#pragma unroll
  for (int r = 0; r < 6; ++r) {
    float f[8];
    ldrow8b(pb + (strip4 + 1 + r) * 44 + cg4, f);
#pragma unroll
    for (int k = 0; k < 4; ++k) {
      int di = r - k;
      if (di >= 0 && di < 3) {
#pragma unroll
        for (int dj = 0; dj < 3; ++dj) {
          float wv = w[di * 3 + dj];
#pragma unroll
          for (int c = 0; c < 4; ++c)
            acc[k * 4 + c] = fmaf(f[c + dj + 1], wv, acc[k * 4 + c]);
        }
        if (BYP && di == 1) {
#pragma unroll
          for (int c = 0; c < 4; ++c)
            by[k * 4 + c] = fmaf(f[c + 2], wb, by[k * 4 + c]);
        }
      }
    }
  }
}

// ---- k_init_p: partial conv3x3(x,Wff) + partial bypass over 16-ci quarter ---
// grid 512 = b(2b) | ochQ(5b) | ciQ(2b); block: 4 och (wave-uniform) x 16 px/thr
__global__ __launch_bounds__(256) void k_init_p(const float* __restrict__ x,
                                                const float* __restrict__ Wff,
                                                const float* __restrict__ Wb,
                                                float* __restrict__ Q,
                                                float* __restrict__ Bq) {
  __shared__ __align__(16) float sS[3168];    // 2 x 36*44
  int tid = threadIdx.x, blk = blockIdx.x;
  int b = blk >> 7, ochQ = (blk >> 2) & 31, ciQ = blk & 3;
  int wv = __builtin_amdgcn_readfirstlane(tid >> 6);
  int och = ochQ * 4 + wv;                    // 0..127
  int strip4 = ((tid >> 3) & 7) * 4;
  int cg4 = (tid & 7) * 4;
  for (int i = tid; i < 3168; i += 256) sS[i] = 0.f;
  int srow = tid >> 3, scg = tid & 7;
  const float* sbase = x + (size_t)(b * 64 + ciQ * 16) * 1024 + srow * 32 + scg * 4;
  float* sd0 = sS + (srow + 2) * 44 + 2 + scg * 4;
  int oc0 = och * 64 + ciQ * 16;              // weight row for local ci=0
  float wA[12], wB[12];
  float acc[16], by[16];
#pragma unroll
  for (int i = 0; i < 16; ++i) { acc[i] = 0.f; by[i] = 0.f; }
  float4 stg = *(const float4*)(sbase);
  wldI(Wff, Wb, oc0, wA);
  __syncthreads();
  stg_write(sd0, stg);
  __syncthreads();
  for (int ci = 0; ci < 16; ci += 2) {
    stg = *(const float4*)(sbase + (size_t)(ci + 1) * 1024);
    wldI(Wff, Wb, oc0 + ci + 1, wB);
    conv16_3<true>(sS, wA, strip4, cg4, acc, by);
    stg_write(sd0 + 1584, stg);
    __syncthreads();
    bool more = (ci + 2 < 16);
    if (more) {
      stg = *(const float4*)(sbase + (size_t)(ci + 2) * 1024);
      wldI(Wff, Wb, oc0 + ci + 2, wA);
    }
    conv16_3<true>(sS + 1584, wB, strip4, cg4, acc, by);
    if (more) stg_write(sd0, stg);
    __syncthreads();
  }
  size_t off = (size_t)ciQ * 524288 + (size_t)(b * 128 + och) * 1024 + strip4 * 32 + cg4;
#pragma unroll
  for (int k = 0; k < 4; ++k) {
    float4 o = {acc[k * 4], acc[k * 4 + 1], acc[k * 4 + 2], acc[k * 4 + 3]};
    float4 bo = {by[k * 4], by[k * 4 + 1], by[k * 4 + 2], by[k * 4 + 3]};
    *(float4*)(Q + off + k * 32) = o;
    *(float4*)(Bq + off + k * 32) = bo;
  }
}

// ---- k_forward_p: partial conv3x3(relu(sum4 Q), Wfb^T) over 16-ci octant ----
// grid 512 = b(2b)|ochQ(4b=16)|ciO(3b=8)
__global__ __launch_bounds__(256) void k_forward_p(const float* __restrict__ Q,
                                                   const float* __restrict__ Wfb,
                                                   float* __restrict__ PA) {
  __shared__ __align__(16) float sS[3168];
  int tid = threadIdx.x, blk = blockIdx.x;
  int b = blk >> 7, ochQ = (blk >> 3) & 15, ciO = blk & 7;
  int wv = __builtin_amdgcn_readfirstlane(tid >> 6);
  int och = ochQ * 4 + wv;                    // 0..63
  int strip4 = ((tid >> 3) & 7) * 4;
  int cg4 = (tid & 7) * 4;
  for (int i = tid; i < 3168; i += 256) sS[i] = 0.f;
  int srow = tid >> 3, scg = tid & 7;
  size_t qbase = (size_t)(b * 128 + ciO * 16) * 1024 + srow * 32 + scg * 4;
  float* sd0 = sS + (srow + 2) * 44 + 2 + scg * 4;
  float wA[12], wB[12];
  float acc[16], dummy[16];
#pragma unroll
  for (int i = 0; i < 16; ++i) acc[i] = 0.f;
#define LDQ(ci) ({ size_t _a = qbase + (size_t)(ci) * 1024; \
    float4 _q0 = *(const float4*)(Q + _a); \
    float4 _q1 = *(const float4*)(Q + 524288 + _a); \
    float4 _q2 = *(const float4*)(Q + 2 * 524288 + _a); \
    float4 _q3 = *(const float4*)(Q + 3 * 524288 + _a); \
    float4 _s; \
    _s.x = _q0.x + _q1.x + _q2.x + _q3.x; \
    _s.y = _q0.y + _q1.y + _q2.y + _q3.y; \
    _s.z = _q0.z + _q1.z + _q2.z + _q3.z; \
    _s.w = _q0.w + _q1.w + _q2.w + _q3.w; \
    _s.x = _s.x > 0.f ? _s.x : 0.f; _s.y = _s.y > 0.f ? _s.y : 0.f; \
    _s.z = _s.z > 0.f ? _s.z : 0.f; _s.w = _s.w > 0.f ? _s.w : 0.f; \
    _s; })
  float4 stg = LDQ(0);
  wldF(Wfb, ciO * 16, och, wA);
  __syncthreads();
  stg_write(sd0, stg);
  __syncthreads();
  for (int ci = 0; ci < 16; ci += 2) {
    stg = LDQ(ci + 1);
    wldF(Wfb, ciO * 16 + ci + 1, och, wB);
    conv16_3<false>(sS, wA, strip4, cg4, acc, dummy);
    stg_write(sd0 + 1584, stg);
    __syncthreads();
    bool more = (ci + 2 < 16);
    if (more) {
      stg = LDQ(ci + 2);
      wldF(Wfb, ciO * 16 + ci + 2, och, wA);
    }
    conv16_3<false>(sS + 1584, wB, strip4, cg4, acc, dummy);
    if (more) stg_write(sd0, stg);
    __syncthreads();
  }
#undef LDQ
  float* dst = PA + (size_t)ciO * 262144 + (size_t)(b * 64 + och) * 1024 + strip4 * 32 + cg4;
#pragma unroll
  for (int k = 0; k < 4; ++k) {
    float4 o = {acc[k * 4], acc[k * 4 + 1], acc[k * 4 + 2], acc[k * 4 + 3]};
    *(float4*)(dst + k * 32) = o;
  }
}

// ---- k_vnorm: v0 = x - sum8(PA); Gam[blk] = block partial of ||v0||^2;
//      also writes out-base = relu(sum4 Q) + sum4 Bq (2 float4 groups/thread)
__global__ __launch_bounds__(256) void k_vnorm(const float* __restrict__ x,
                                               const float* __restrict__ PA,
                                               const float* __restrict__ Q,
                                               const float* __restrict__ Bq,
                                               float* __restrict__ v0out,
                                               float* __restrict__ Gam,
                                               float* __restrict__ out) {
  __shared__ float ws[4];
  int tid = threadIdx.x;
  size_t i = (size_t)(blockIdx.x * 256 + tid) * 4;
  float4 s = {0.f, 0.f, 0.f, 0.f};
#pragma unroll
  for (int o = 0; o < 8; ++o) {
    float4 q = *(const float4*)(PA + (size_t)o * 262144 + i);
    s.x += q.x; s.y += q.y; s.z += q.z; s.w += q.w;
  }
  float4 xv = *(const float4*)(x + i);
  float4 v = {xv.x - s.x, xv.y - s.y, xv.z - s.z, xv.w - s.w};
  *(float4*)(v0out + i) = v;
  float g = v.x * v.x + v.y * v.y + v.z * v.z + v.w * v.w;
  // out-base: out-space is 2x v-space -> 2 groups per thread
#pragma unroll
  for (int rep = 0; rep < 2; ++rep) {
    size_t j = (size_t)rep * 262144 + i;
    float4 qs = {0.f, 0.f, 0.f, 0.f}, bs = {0.f, 0.f, 0.f, 0.f};
#pragma unroll
    for (int q = 0; q < 4; ++q) {
      float4 a = *(const float4*)(Q + (size_t)q * 524288 + j);
      float4 c = *(const float4*)(Bq + (size_t)q * 524288 + j);
      qs.x += a.x; qs.y += a.y; qs.z += a.z; qs.w += a.w;
      bs.x += c.x; bs.y += c.y; bs.z += c.z; bs.w += c.w;
    }
    qs.x = (qs.x > 0.f ? qs.x : 0.f) + bs.x;
    qs.y = (qs.y > 0.f ? qs.y : 0.f) + bs.y;
    qs.z = (qs.z > 0.f ? qs.z : 0.f) + bs.z;
    qs.w = (qs.w > 0.f ? qs.w : 0.f) + bs.w;
    *(float4*)(out + j) = qs;
  }
#pragma unroll
  for (int d = 32; d; d >>= 1) g += __shfl_down(g, d, 64);
  if ((tid & 63) == 0) ws[tid >> 6] = g;
  __syncthreads();
  if (tid == 0) Gam[blockIdx.x] = ws[0] + ws[1] + ws[2] + ws[3];
}

// ---- k_finalize_p: partial conv3x3(d0*v0, flip(Wfb)) over 16-ci quarter,
//      atomicAdd into out (base written by k_vnorm). Gam[256] reduced here.
// grid 512 = b(2b)|coQ(5b)|ciQ(2b).
__global__ __launch_bounds__(256) void k_finalize_p(const float* __restrict__ V,
                                                    const float* __restrict__ Gam,
                                                    const float* __restrict__ Wfb,
                                                    float* __restrict__ out) {
  __shared__ __align__(16) float sS[3168];
  __shared__ float ws[4];
  int tid = threadIdx.x, blk = blockIdx.x;
  int b = blk >> 7, coQ = (blk >> 2) & 31, ciQ = blk & 3;
  int wv = __builtin_amdgcn_readfirstlane(tid >> 6);
  int co = coQ * 4 + wv;                      // 0..127
  int strip4 = ((tid >> 3) & 7) * 4;
  int cg4 = (tid & 7) * 4;
  // reduce Gam[0..255] -> g00 (deterministic, no atomic, no pre-zero)
  float g = Gam[tid];
#pragma unroll
  for (int d = 32; d; d >>= 1) g += __shfl_down(g, d, 64);
  if ((tid & 63) == 0) ws[tid >> 6] = g;
  for (int i = tid; i < 3168; i += 256) sS[i] = 0.f;
  int srow = tid >> 3, scg = tid & 7;
  size_t sb_off = (size_t)(b * 64 + ciQ * 16) * 1024 + srow * 32 + scg * 4;
  const float* v0b = V + sb_off;
  float* sd0 = sS + (srow + 2) * 44 + 2 + scg * 4;
  float wA[12], wB[12];
  float acc[16], dummy[16];
#pragma unroll
  for (int i = 0; i < 16; ++i) acc[i] = 0.f;
  float4 raw = *(const float4*)(v0b);
  wldZ(Wfb, co, ciQ * 16, wA);
  __syncthreads();                            // covers ws[] + sS zero-fill
  float d0 = ((float)NUM_ITERS * LR_F) *
             __builtin_amdgcn_rsqf(ws[0] + ws[1] + ws[2] + ws[3]);
#define LOADS(off) ({ \
    float4 _a = *(const float4*)(v0b + (off)); \
    float4 _s = {d0 * _a.x, d0 * _a.y, d0 * _a.z, d0 * _a.w}; \
    _s; })
  float4 stg = {d0 * raw.x, d0 * raw.y, d0 * raw.z, d0 * raw.w};
  stg_write(sd0, stg);
  __syncthreads();
  for (int ci = 0; ci < 16; ci += 2) {
    stg = LOADS((size_t)(ci + 1) * 1024);
    wldZ(Wfb, co, ciQ * 16 + ci + 1, wB);
    conv16_3<false>(sS, wA, strip4, cg4, acc, dummy);
    stg_write(sd0 + 1584, stg);
    __syncthreads();
    bool more = (ci + 2 < 16);
    if (more) {
      stg = LOADS((size_t)(ci + 2) * 1024);
      wldZ(Wfb, co, ciQ * 16 + ci + 2, wA);
    }
    conv16_3<false>(sS + 1584, wB, strip4, cg4, acc, dummy);
    if (more) stg_write(sd0, stg);
    __syncthreads();
  }
#undef LOADS
  size_t off = (size_t)(b * 128 + co) * 1024 + strip4 * 32 + cg4;
#pragma unroll
  for (int k = 0; k < 4; ++k)
#pragma unroll
    for (int c = 0; c < 4; ++c)
      atomicAdd(out + off + k * 32 + c, acc[k * 4 + c]);
}

// ---- launch -----------------------------------------------------------------
extern "C" void kernel_launch(void* const* d_in, const int* in_sizes, int n_in,
                              void* d_out, int out_size, void* d_ws, size_t ws_size,
                              hipStream_t stream) {
  const float* x   = (const float*)d_in[0];
  const float* Wff = (const float*)d_in[1];
  const float* Wfb = (const float*)d_in[2];
  const float* Wb  = (const float*)d_in[3];
  float* out = (float*)d_out;

  float* V    = (float*)d_ws;                  // 262144 (v0)
  float* Gam  = V + VPLANE;                    // 256 block partials
  float* PA   = Gam + 256;                     // 8 * 262144
  float* Q    = PA + (size_t)8 * 262144;       // 4 * 524288
  float* Bq   = Q + (size_t)4 * 524288;        // 4 * 524288

  hipLaunchKernelGGL(k_init_p,     dim3(512), dim3(256), 0, stream, x, Wff, Wb, Q, Bq);
  hipLaunchKernelGGL(k_forward_p,  dim3(512), dim3(256), 0, stream, Q, Wfb, PA);
  hipLaunchKernelGGL(k_vnorm,      dim3(256), dim3(256), 0, stream, x, PA, Q, Bq, V, Gam, out);
  hipLaunchKernelGGL(k_finalize_p, dim3(512), dim3(256), 0, stream, V, Gam, Wfb, out);
}

// Round 2
// 147.668 us; speedup vs baseline: 1.1234x; 1.1234x over previous
//
#include <hip/hip_runtime.h>

#define NUM_ITERS 500
#define LR_F 0.001f
#define VPLANE 262144    // 4*64*1024 floats
// K=1 Krylov truncation: s = d0*v0, d0 = 500*LR/||v0||.
// R18 conv tap structure retained (session optimum). Deep-staging (R19),
// ci-splits (R14), row-splits (R15) regressed: do not re-attempt.
// R20 lessons: k_prep removal + vnorm-out-base GOOD (kept); atomicAdd
// epilogue BAD (33MB write amplification) -> reverted to Fp + k_fsum2.
// R21 (this round):
//  - LDS skew: pitch 44 -> 48 with row skew ((R>>2)&3)*4. Old layout was a
//    4-way bank conflict on every ds_read_b128 (phase 16g, 2 values over 8
//    groups; 7.86M conflict cycles = 26% of kernel). Skew gives phases
//    {0,4,8,12}x2 = 2-way = free. Applied to both write and read paths.
//  - __launch_bounds__(256,2) on conv kernels: VGPR was capped at 64,
//    forcing serialized ds_read->FMA chains (VALUBusy 9.7%). Grid gives only
//    2 blocks/CU = 2 waves/SIMD, so 256-VGPR budget costs nothing.

// ---- register-safe unpack helpers -------------------------------------------
__device__ __forceinline__ void ldrow8b(const float* __restrict__ rp, float f[8]) {
  float4 a = *(const float4*)(rp);
  float4 b = *(const float4*)(rp + 4);
  f[0] = a.x; f[1] = a.y; f[2] = a.z; f[3] = a.w;
  f[4] = b.x; f[5] = b.y; f[6] = b.z; f[7] = b.w;
}

__device__ __forceinline__ void stg_write(float* sd, float4 v) {
  float2 u = {v.x, v.y}, w = {v.z, v.w};
  *(float2*)sd = u;
  *(float2*)(sd + 2) = w;
}

// ---- raw weight loads (wave-uniform addresses -> scalar loads) --------------
__device__ __forceinline__ void wldI(const float* __restrict__ Wff,
                                     const float* __restrict__ Wb,
                                     int oc, float w[12]) {
  const float* s = Wff + (size_t)oc * 9;
#pragma unroll
  for (int k = 0; k < 9; ++k) w[k] = s[k];
  w[9] = Wb[oc];
}
__device__ __forceinline__ void wldF(const float* __restrict__ Wfb,
                                     int ci, int och, float w[12]) {
  const float* s = Wfb + ((size_t)ci * 64 + och) * 9;
#pragma unroll
  for (int k = 0; k < 9; ++k) w[k] = s[k];
  w[9] = 0.f;
}
__device__ __forceinline__ void wldZ(const float* __restrict__ Wfb,
                                     int co, int ci, float w[12]) {
  const float* s = Wfb + ((size_t)co * 64 + ci) * 9;
#pragma unroll
  for (int k = 0; k < 9; ++k) w[k] = s[8 - k];
  w[9] = 0.f;
}

// ---- skewed LDS geometry ----------------------------------------------------
// pitch 48 floats, row skew ((R>>2)&3)*4; plane stride 1744 floats, 2 planes.
#define SPITCH 48
#define SPLANE 1744
#define SLDS   3488
__device__ __forceinline__ int srow_off(int R) {
  return R * SPITCH + ((R >> 2) & 3) * 4;
}

// ---- conv16_3: 3x3 pad1 over full-plane LDS (skewed), 16 px ----------------
template <bool BYP>
__device__ __forceinline__ void conv16_3(const float* __restrict__ pb, const float w[12],
                                         const int ro[6], float acc[16], float by[16]) {
  float wb = w[9];
#pragma unroll
  for (int r = 0; r < 6; ++r) {
    float f[8];
    ldrow8b(pb + ro[r], f);
#pragma unroll
    for (int k = 0; k < 4; ++k) {
      int di = r - k;
      if (di >= 0 && di < 3) {
#pragma unroll
        for (int dj = 0; dj < 3; ++dj) {
          float wv = w[di * 3 + dj];
#pragma unroll
        for (int c = 0; c < 4; ++c)
            acc[k * 4 + c] = fmaf(f[c + dj + 1], wv, acc[k * 4 + c]);
        }
        if (BYP && di == 1) {
#pragma unroll
          for (int c = 0; c < 4; ++c)
            by[k * 4 + c] = fmaf(f[c + 2], wb, by[k * 4 + c]);
        }
      }
    }
  }
}

// ---- k_init_p: partial conv3x3(x,Wff) + partial bypass over 16-ci quarter ---
// grid 512 = b(4) | ochQ(32) | ciQ(4); block: 4 och (wave-uniform) x 16 px/thr
__global__ __launch_bounds__(256, 2) void k_init_p(const float* __restrict__ x,
                                                   const float* __restrict__ Wff,
                                                   const float* __restrict__ Wb,
                                                   float* __restrict__ Q,
                                                   float* __restrict__ Bq) {
  __shared__ __align__(16) float sS[SLDS];
  int tid = threadIdx.x, blk = blockIdx.x;
  int b = blk >> 7, ochQ = (blk >> 2) & 31, ciQ = blk & 3;
  int wv = __builtin_amdgcn_readfirstlane(tid >> 6);
  int och = ochQ * 4 + wv;                    // 0..127
  int strip4 = ((tid >> 3) & 7) * 4;
  int cg4 = (tid & 7) * 4;
  int ro[6];
#pragma unroll
  for (int r = 0; r < 6; ++r) ro[r] = srow_off(strip4 + 1 + r) + cg4;
  for (int i = tid; i < SLDS; i += 256) sS[i] = 0.f;
  int srow = tid >> 3, scg = tid & 7;
  const float* sbase = x + (size_t)(b * 64 + ciQ * 16) * 1024 + srow * 32 + scg * 4;
  float* sd0 = sS + srow_off(srow + 2) + 2 + scg * 4;
  int oc0 = och * 64 + ciQ * 16;
  float wA[12], wB[12];
  float acc[16], by[16];
#pragma unroll
  for (int i = 0; i < 16; ++i) { acc[i] = 0.f; by[i] = 0.f; }
  float4 stg = *(const float4*)(sbase);
  wldI(Wff, Wb, oc0, wA);
  __syncthreads();
  stg_write(sd0, stg);
  __syncthreads();
  for (int ci = 0; ci < 16; ci += 2) {
    stg = *(const float4*)(sbase + (size_t)(ci + 1) * 1024);
    wldI(Wff, Wb, oc0 + ci + 1, wB);
    conv16_3<true>(sS, wA, ro, acc, by);
    stg_write(sd0 + SPLANE, stg);
    __syncthreads();
    bool more = (ci + 2 < 16);
    if (more) {
      stg = *(const float4*)(sbase + (size_t)(ci + 2) * 1024);
      wldI(Wff, Wb, oc0 + ci + 2, wA);
    }
    conv16_3<true>(sS + SPLANE, wB, ro, acc, by);
    if (more) stg_write(sd0, stg);
    __syncthreads();
  }
  size_t off = (size_t)ciQ * 524288 + (size_t)(b * 128 + och) * 1024 + strip4 * 32 + cg4;
#pragma unroll
  for (int k = 0; k < 4; ++k) {
    float4 o = {acc[k * 4], acc[k * 4 + 1], acc[k * 4 + 2], acc[k * 4 + 3]};
    float4 bo = {by[k * 4], by[k * 4 + 1], by[k * 4 + 2], by[k * 4 + 3]};
    *(float4*)(Q + off + k * 32) = o;
    *(float4*)(Bq + off + k * 32) = bo;
  }
}

// ---- k_forward_p: partial conv3x3(relu(sum4 Q), Wfb^T) over 16-ci octant ----
// grid 512 = b(4)|ochQ(16)|ciO(8)
__global__ __launch_bounds__(256, 2) void k_forward_p(const float* __restrict__ Q,
                                                      const float* __restrict__ Wfb,
                                                      float* __restrict__ PA) {
  __shared__ __align__(16) float sS[SLDS];
  int tid = threadIdx.x, blk = blockIdx.x;
  int b = blk >> 7, ochQ = (blk >> 3) & 15, ciO = blk & 7;
  int wv = __builtin_amdgcn_readfirstlane(tid >> 6);
  int och = ochQ * 4 + wv;                    // 0..63
  int strip4 = ((tid >> 3) & 7) * 4;
  int cg4 = (tid & 7) * 4;
  int ro[6];
#pragma unroll
  for (int r = 0; r < 6; ++r) ro[r] = srow_off(strip4 + 1 + r) + cg4;
  for (int i = tid; i < SLDS; i += 256) sS[i] = 0.f;
  int srow = tid >> 3, scg = tid & 7;
  size_t qbase = (size_t)(b * 128 + ciO * 16) * 1024 + srow * 32 + scg * 4;
  float* sd0 = sS + srow_off(srow + 2) + 2 + scg * 4;
  float wA[12], wB[12];
  float acc[16], dummy[16];
#pragma unroll
  for (int i = 0; i < 16; ++i) acc[i] = 0.f;
#define LDQ(ci) ({ size_t _a = qbase + (size_t)(ci) * 1024; \
    float4 _q0 = *(const float4*)(Q + _a); \
    float4 _q1 = *(const float4*)(Q + 524288 + _a); \
    float4 _q2 = *(const float4*)(Q + 2 * 524288 + _a); \
    float4 _q3 = *(const float4*)(Q + 3 * 524288 + _a); \
    float4 _s; \
    _s.x = _q0.x + _q1.x + _q2.x + _q3.x; \
    _s.y = _q0.y + _q1.y + _q2.y + _q3.y; \
    _s.z = _q0.z + _q1.z + _q2.z + _q3.z; \
    _s.w = _q0.w + _q1.w + _q2.w + _q3.w; \
    _s.x = _s.x > 0.f ? _s.x : 0.f; _s.y = _s.y > 0.f ? _s.y : 0.f; \
    _s.z = _s.z > 0.f ? _s.z : 0.f; _s.w = _s.w > 0.f ? _s.w : 0.f; \
    _s; })
  float4 stg = LDQ(0);
  wldF(Wfb, ciO * 16, och, wA);
  __syncthreads();
  stg_write(sd0, stg);
  __syncthreads();
  for (int ci = 0; ci < 16; ci += 2) {
    stg = LDQ(ci + 1);
    wldF(Wfb, ciO * 16 + ci + 1, och, wB);
    conv16_3<false>(sS, wA, ro, acc, dummy);
    stg_write(sd0 + SPLANE, stg);
    __syncthreads();
    bool more = (ci + 2 < 16);
    if (more) {
      stg = LDQ(ci + 2);
      wldF(Wfb, ciO * 16 + ci + 2, och, wA);
    }
    conv16_3<false>(sS + SPLANE, wB, ro, acc, dummy);
    if (more) stg_write(sd0, stg);
    __syncthreads();
  }
#undef LDQ
  float* dst = PA + (size_t)ciO * 262144 + (size_t)(b * 64 + och) * 1024 + strip4 * 32 + cg4;
#pragma unroll
  for (int k = 0; k < 4; ++k) {
    float4 o = {acc[k * 4], acc[k * 4 + 1], acc[k * 4 + 2], acc[k * 4 + 3]};
    *(float4*)(dst + k * 32) = o;
  }
}

// ---- k_vnorm: v0 = x - sum8(PA); Gam[blk] = block partial of ||v0||^2;
//      also writes out-base = relu(sum4 Q) + sum4 Bq
__global__ __launch_bounds__(256) void k_vnorm(const float* __restrict__ x,
                                               const float* __restrict__ PA,
                                               const float* __restrict__ Q,
                                               const float* __restrict__ Bq,
                                               float* __restrict__ v0out,
                                               float* __restrict__ Gam,
                                               float* __restrict__ out) {
  __shared__ float ws[4];
  int tid = threadIdx.x;
  size_t i = (size_t)(blockIdx.x * 256 + tid) * 4;
  float4 s = {0.f, 0.f, 0.f, 0.f};
#pragma unroll
  for (int o = 0; o < 8; ++o) {
    float4 q = *(const float4*)(PA + (size_t)o * 262144 + i);
    s.x += q.x; s.y += q.y; s.z += q.z; s.w += q.w;
  }
  float4 xv = *(const float4*)(x + i);
  float4 v = {xv.x - s.x, xv.y - s.y, xv.z - s.z, xv.w - s.w};
  *(float4*)(v0out + i) = v;
  float g = v.x * v.x + v.y * v.y + v.z * v.z + v.w * v.w;
#pragma unroll
  for (int rep = 0; rep < 2; ++rep) {
    size_t j = (size_t)rep * 262144 + i;
    float4 qs = {0.f, 0.f, 0.f, 0.f}, bs = {0.f, 0.f, 0.f, 0.f};
#pragma unroll
    for (int q = 0; q < 4; ++q) {
      float4 a = *(const float4*)(Q + (size_t)q * 524288 + j);
      float4 c = *(const float4*)(Bq + (size_t)q * 524288 + j);
      qs.x += a.x; qs.y += a.y; qs.z += a.z; qs.w += a.w;
      bs.x += c.x; bs.y += c.y; bs.z += c.z; bs.w += c.w;
    }
    qs.x = (qs.x > 0.f ? qs.x : 0.f) + bs.x;
    qs.y = (qs.y > 0.f ? qs.y : 0.f) + bs.y;
    qs.z = (qs.z > 0.f ? qs.z : 0.f) + bs.z;
    qs.w = (qs.w > 0.f ? qs.w : 0.f) + bs.w;
    *(float4*)(out + j) = qs;
  }
#pragma unroll
  for (int d = 32; d; d >>= 1) g += __shfl_down(g, d, 64);
  if ((tid & 63) == 0) ws[tid >> 6] = g;
  __syncthreads();
  if (tid == 0) Gam[blockIdx.x] = ws[0] + ws[1] + ws[2] + ws[3];
}

// ---- k_finalize_p: partial conv3x3(d0*v0, flip(Wfb)) over 16-ci quarter ----
// grid 512 = b(4)|coQ(32)|ciQ(4). Gam[256] reduced here. Writes Fp partials.
__global__ __launch_bounds__(256, 2) void k_finalize_p(const float* __restrict__ V,
                                                       const float* __restrict__ Gam,
                                                       const float* __restrict__ Wfb,
                                                       float* __restrict__ Fp) {
  __shared__ __align__(16) float sS[SLDS];
  __shared__ float ws[4];
  int tid = threadIdx.x, blk = blockIdx.x;
  int b = blk >> 7, coQ = (blk >> 2) & 31, ciQ = blk & 3;
  int wv = __builtin_amdgcn_readfirstlane(tid >> 6);
  int co = coQ * 4 + wv;                      // 0..127
  int strip4 = ((tid >> 3) & 7) * 4;
  int cg4 = (tid & 7) * 4;
  int ro[6];
#pragma unroll
  for (int r = 0; r < 6; ++r) ro[r] = srow_off(strip4 + 1 + r) + cg4;
  // reduce Gam[0..255] -> g00 (deterministic, no atomic, no pre-zero)
  float g = Gam[tid];
#pragma unroll
  for (int d = 32; d; d >>= 1) g += __shfl_down(g, d, 64);
  if ((tid & 63) == 0) ws[tid >> 6] = g;
  for (int i = tid; i < SLDS; i += 256) sS[i] = 0.f;
  int srow = tid >> 3, scg = tid & 7;
  size_t sb_off = (size_t)(b * 64 + ciQ * 16) * 1024 + srow * 32 + scg * 4;
  const float* v0b = V + sb_off;
  float* sd0 = sS + srow_off(srow + 2) + 2 + scg * 4;
  float wA[12], wB[12];
  float acc[16], dummy[16];
#pragma unroll
  for (int i = 0; i < 16; ++i) acc[i] = 0.f;
  float4 raw = *(const float4*)(v0b);
  wldZ(Wfb, co, ciQ * 16, wA);
  __syncthreads();                            // covers ws[] + sS zero-fill
  float d0 = ((float)NUM_ITERS * LR_F) *
             __builtin_amdgcn_rsqf(ws[0] + ws[1] + ws[2] + ws[3]);
#define LOADS(off) ({ \
    float4 _a = *(const float4*)(v0b + (off)); \
    float4 _s = {d0 * _a.x, d0 * _a.y, d0 * _a.z, d0 * _a.w}; \
    _s; })
  float4 stg = {d0 * raw.x, d0 * raw.y, d0 * raw.z, d0 * raw.w};
  stg_write(sd0, stg);
  __syncthreads();
  for (int ci = 0; ci < 16; ci += 2) {
    stg = LOADS((size_t)(ci + 1) * 1024);
    wldZ(Wfb, co, ciQ * 16 + ci + 1, wB);
    conv16_3<false>(sS, wA, ro, acc, dummy);
    stg_write(sd0 + SPLANE, stg);
    __syncthreads();
    bool more = (ci + 2 < 16);
    if (more) {
      stg = LOADS((size_t)(ci + 2) * 1024);
      wldZ(Wfb, co, ciQ * 16 + ci + 2, wA);
    }
    conv16_3<false>(sS + SPLANE, wB, ro, acc, dummy);
    if (more) stg_write(sd0, stg);
    __syncthreads();
  }
#undef LOADS
  size_t off = (size_t)ciQ * 524288 + (size_t)(b * 128 + co) * 1024 + strip4 * 32 + cg4;
#pragma unroll
  for (int k = 0; k < 4; ++k) {
    float4 o = {acc[k * 4], acc[k * 4 + 1], acc[k * 4 + 2], acc[k * 4 + 3]};
    *(float4*)(Fp + off + k * 32) = o;
  }
}

// ---- k_fsum2: out += sum4 Fp (base written by k_vnorm) ----------------------
__global__ __launch_bounds__(256) void k_fsum2(const float* __restrict__ Fp,
                                               float* __restrict__ out) {
  size_t i = (size_t)(blockIdx.x * 256 + threadIdx.x) * 4;
  float4 s = *(const float4*)(out + i);
#pragma unroll
  for (int q = 0; q < 4; ++q) {
    float4 p = *(const float4*)(Fp + (size_t)q * 524288 + i);
    s.x += p.x; s.y += p.y; s.z += p.z; s.w += p.w;
  }
  *(float4*)(out + i) = s;
}

// ---- launch -----------------------------------------------------------------
extern "C" void kernel_launch(void* const* d_in, const int* in_sizes, int n_in,
                              void* d_out, int out_size, void* d_ws, size_t ws_size,
                              hipStream_t stream) {
  const float* x   = (const float*)d_in[0];
  const float* Wff = (const float*)d_in[1];
  const float* Wfb = (const float*)d_in[2];
  const float* Wb  = (const float*)d_in[3];
  float* out = (float*)d_out;

  float* V    = (float*)d_ws;                  // 262144 (v0)
  float* Gam  = V + VPLANE;                    // 256 block partials
  float* PA   = Gam + 256;                     // 8 * 262144
  float* Q    = PA + (size_t)8 * 262144;       // 4 * 524288
  float* Bq   = Q + (size_t)4 * 524288;        // 4 * 524288
  float* Fp   = Bq + (size_t)4 * 524288;       // 4 * 524288

  hipLaunchKernelGGL(k_init_p,     dim3(512), dim3(256), 0, stream, x, Wff, Wb, Q, Bq);
  hipLaunchKernelGGL(k_forward_p,  dim3(512), dim3(256), 0, stream, Q, Wfb, PA);
  hipLaunchKernelGGL(k_vnorm,      dim3(256), dim3(256), 0, stream, x, PA, Q, Bq, V, Gam, out);
  hipLaunchKernelGGL(k_finalize_p, dim3(512), dim3(256), 0, stream, V, Gam, Wfb, Fp);
  hipLaunchKernelGGL(k_fsum2,      dim3(512), dim3(256), 0, stream, Fp, out);
}

// Round 3
// 118.392 us; speedup vs baseline: 1.4012x; 1.2473x over previous
//
#include <hip/hip_runtime.h>

#define NUM_ITERS 500
#define LR_F 0.001f
#define VPLANE 262144    // 4*64*1024 floats
// K=1 Krylov truncation: s = d0*v0, d0 = 500*LR/||v0||.
// R20: k_prep removed (scalar weight loads), Gam via block partials. GOOD.
//      atomicAdd epilogue BAD (33MB write amp) -> Fp + k_fsum2.
// R21: LDS pitch-skew + launch_bounds ~NEUTRAL -> bank-phase theory falsified;
//      both layouts already wave-balanced. Real cost = LDS round-trip:
//      32 barrier phases/block, vmcnt(0) drains, 2 waves/SIMD, VALUBusy 9.7%.
// R22 (this round): REGISTER-DIRECT conv. No LDS plane, no barriers.
//      Each thread loads its 6 rows as one aligned float4 (cols 4cg..4cg+3)
//      straight from global (4KB plane is L1-resident, reused by all waves);
//      halo cols via __shfl_up/down from neighbor lanes; edge rows/cols
//      clamped+zero-selected. relu(sum4 Q) hoisted to k_ysum (also writes
//      out-base). FP tap order identical to R18 -> absmax unchanged.

// ---- raw weight loads (wave-uniform addresses -> scalar loads) --------------
__device__ __forceinline__ void wldI(const float* __restrict__ Wff,
                                     const float* __restrict__ Wb,
                                     int oc, float w[12]) {
  const float* s = Wff + (size_t)oc * 9;
#pragma unroll
  for (int k = 0; k < 9; ++k) w[k] = s[k];
  w[9] = Wb[oc];
}
__device__ __forceinline__ void wldF(const float* __restrict__ Wfb,
                                     int ci, int och, float w[12]) {
  const float* s = Wfb + ((size_t)ci * 64 + och) * 9;
#pragma unroll
  for (int k = 0; k < 9; ++k) w[k] = s[k];
  w[9] = 0.f;
}
__device__ __forceinline__ void wldZ(const float* __restrict__ Wfb,
                                     int co, int ci, float w[12]) {
  const float* s = Wfb + ((size_t)co * 64 + ci) * 9;
#pragma unroll
  for (int k = 0; k < 9; ++k) w[k] = s[8 - k];
  w[9] = 0.f;
}

// ---- conv16_reg: 3x3 pad1 conv of one 32x32 plane, register-direct ----------
// Thread owns 4 rows (strip4..strip4+3) x 4 cols (4cg..4cg+3). Per input row r
// (image row strip4+r-1): one aligned float4 + 2 shfl for halo cols.
// fv[i] = image col 4cg + i - 1;  output col c tap dj reads fv[c+dj].
template <bool BYP, bool SCALE>
__device__ __forceinline__ void conv16_reg(const float* __restrict__ plane,
                                           const float w[12], float d0,
                                           int strip4, int cg4, bool cg0, bool cg7,
                                           float acc[16], float by[16]) {
  float wb = w[9];
#pragma unroll
  for (int r = 0; r < 6; ++r) {
    int R = strip4 + r - 1;
    float4 f4;
    if (r == 0) {
      bool ok = R >= 0;
      f4 = *(const float4*)(plane + (ok ? R : 0) * 32 + cg4);
      f4.x = ok ? f4.x : 0.f; f4.y = ok ? f4.y : 0.f;
      f4.z = ok ? f4.z : 0.f; f4.w = ok ? f4.w : 0.f;
    } else if (r == 5) {
      bool ok = R < 32;
      f4 = *(const float4*)(plane + (ok ? R : 31) * 32 + cg4);
      f4.x = ok ? f4.x : 0.f; f4.y = ok ? f4.y : 0.f;
      f4.z = ok ? f4.z : 0.f; f4.w = ok ? f4.w : 0.f;
    } else {
      f4 = *(const float4*)(plane + R * 32 + cg4);
    }
    if (SCALE) { f4.x *= d0; f4.y *= d0; f4.z *= d0; f4.w *= d0; }
    float fl = __shfl_up(f4.w, 1, 64);     // lane-1's col 4cg+3 == our 4cg-1
    float fr = __shfl_down(f4.x, 1, 64);   // lane+1's col 4cg   == our 4cg+4
    fl = cg0 ? 0.f : fl;
    fr = cg7 ? 0.f : fr;
    float fv[6] = {fl, f4.x, f4.y, f4.z, f4.w, fr};
#pragma unroll
    for (int k = 0; k < 4; ++k) {
      int di = r - k;
      if (di >= 0 && di < 3) {
#pragma unroll
        for (int dj = 0; dj < 3; ++dj) {
          float wv = w[di * 3 + dj];
#pragma unroll
          for (int c = 0; c < 4; ++c)
            acc[k * 4 + c] = fmaf(fv[c + dj], wv, acc[k * 4 + c]);
        }
        if (BYP && di == 1) {
#pragma unroll
          for (int c = 0; c < 4; ++c)
            by[k * 4 + c] = fmaf(fv[c + 1], wb, by[k * 4 + c]);
        }
      }
    }
  }
}

// ---- k_init_p: partial conv3x3(x,Wff) + partial bypass over 16-ci quarter ---
// grid 512 = b(4) | ochQ(32) | ciQ(4); block: 4 och (wave-uniform) x 16 px/thr
__global__ __launch_bounds__(256, 2) void k_init_p(const float* __restrict__ x,
                                                   const float* __restrict__ Wff,
                                                   const float* __restrict__ Wb,
                                                   float* __restrict__ Q,
                                                   float* __restrict__ Bq) {
  int tid = threadIdx.x, blk = blockIdx.x;
  int b = blk >> 7, ochQ = (blk >> 2) & 31, ciQ = blk & 3;
  int wv = __builtin_amdgcn_readfirstlane(tid >> 6);
  int och = ochQ * 4 + wv;                    // 0..127
  int strip4 = ((tid >> 3) & 7) * 4;
  int cg4 = (tid & 7) * 4;
  bool cg0 = (tid & 7) == 0, cg7 = (tid & 7) == 7;
  const float* pb = x + (size_t)(b * 64 + ciQ * 16) * 1024;
  int oc0 = och * 64 + ciQ * 16;
  float wA[12], wB[12];
  float acc[16], by[16];
#pragma unroll
  for (int i = 0; i < 16; ++i) { acc[i] = 0.f; by[i] = 0.f; }
  wldI(Wff, Wb, oc0, wA);
  for (int ci = 0; ci < 16; ci += 2) {
    wldI(Wff, Wb, oc0 + ci + 1, wB);
    conv16_reg<true, false>(pb + (size_t)ci * 1024, wA, 0.f, strip4, cg4, cg0, cg7, acc, by);
    if (ci + 2 < 16) wldI(Wff, Wb, oc0 + ci + 2, wA);
    conv16_reg<true, false>(pb + (size_t)(ci + 1) * 1024, wB, 0.f, strip4, cg4, cg0, cg7, acc, by);
  }
  size_t off = (size_t)ciQ * 524288 + (size_t)(b * 128 + och) * 1024 + strip4 * 32 + cg4;
#pragma unroll
  for (int k = 0; k < 4; ++k) {
    float4 o = {acc[k * 4], acc[k * 4 + 1], acc[k * 4 + 2], acc[k * 4 + 3]};
    float4 bo = {by[k * 4], by[k * 4 + 1], by[k * 4 + 2], by[k * 4 + 3]};
    *(float4*)(Q + off + k * 32) = o;
    *(float4*)(Bq + off + k * 32) = bo;
  }
}

// ---- k_ysum: Y = relu(sum4 Q); out-base = Y + sum4 Bq ----------------------
__global__ __launch_bounds__(256) void k_ysum(const float* __restrict__ Q,
                                              const float* __restrict__ Bq,
                                              float* __restrict__ Y,
                                              float* __restrict__ out) {
  size_t i = (size_t)(blockIdx.x * 256 + threadIdx.x) * 4;
  float4 qs = {0.f, 0.f, 0.f, 0.f}, bs = {0.f, 0.f, 0.f, 0.f};
#pragma unroll
  for (int q = 0; q < 4; ++q) {
    float4 a = *(const float4*)(Q + (size_t)q * 524288 + i);
    float4 c = *(const float4*)(Bq + (size_t)q * 524288 + i);
    qs.x += a.x; qs.y += a.y; qs.z += a.z; qs.w += a.w;
    bs.x += c.x; bs.y += c.y; bs.z += c.z; bs.w += c.w;
  }
  qs.x = qs.x > 0.f ? qs.x : 0.f; qs.y = qs.y > 0.f ? qs.y : 0.f;
  qs.z = qs.z > 0.f ? qs.z : 0.f; qs.w = qs.w > 0.f ? qs.w : 0.f;
  *(float4*)(Y + i) = qs;
  float4 ob = {qs.x + bs.x, qs.y + bs.y, qs.z + bs.z, qs.w + bs.w};
  *(float4*)(out + i) = ob;
}

// ---- k_forward_p: partial conv3x3(Y, Wfb^T) over 16-ci octant --------------
// grid 512 = b(4)|ochQ(16)|ciO(8)
__global__ __launch_bounds__(256, 2) void k_forward_p(const float* __restrict__ Y,
                                                      const float* __restrict__ Wfb,
                                                      float* __restrict__ PA) {
  int tid = threadIdx.x, blk = blockIdx.x;
  int b = blk >> 7, ochQ = (blk >> 3) & 15, ciO = blk & 7;
  int wv = __builtin_amdgcn_readfirstlane(tid >> 6);
  int och = ochQ * 4 + wv;                    // 0..63
  int strip4 = ((tid >> 3) & 7) * 4;
  int cg4 = (tid & 7) * 4;
  bool cg0 = (tid & 7) == 0, cg7 = (tid & 7) == 7;
  const float* pb = Y + (size_t)(b * 128 + ciO * 16) * 1024;
  float wA[12], wB[12];
  float acc[16], dummy[16];
#pragma unroll
  for (int i = 0; i < 16; ++i) acc[i] = 0.f;
  wldF(Wfb, ciO * 16, och, wA);
  for (int ci = 0; ci < 16; ci += 2) {
    wldF(Wfb, ciO * 16 + ci + 1, och, wB);
    conv16_reg<false, false>(pb + (size_t)ci * 1024, wA, 0.f, strip4, cg4, cg0, cg7, acc, dummy);
    if (ci + 2 < 16) wldF(Wfb, ciO * 16 + ci + 2, och, wA);
    conv16_reg<false, false>(pb + (size_t)(ci + 1) * 1024, wB, 0.f, strip4, cg4, cg0, cg7, acc, dummy);
  }
  float* dst = PA + (size_t)ciO * 262144 + (size_t)(b * 64 + och) * 1024 + strip4 * 32 + cg4;
#pragma unroll
  for (int k = 0; k < 4; ++k) {
    float4 o = {acc[k * 4], acc[k * 4 + 1], acc[k * 4 + 2], acc[k * 4 + 3]};
    *(float4*)(dst + k * 32) = o;
  }
}

// ---- k_vnorm: v0 = x - sum8(PA); Gam[blk] = block partial of ||v0||^2 ------
__global__ __launch_bounds__(256) void k_vnorm(const float* __restrict__ x,
                                               const float* __restrict__ PA,
                                               float* __restrict__ v0out,
                                               float* __restrict__ Gam) {
  __shared__ float ws[4];
  int tid = threadIdx.x;
  size_t i = (size_t)(blockIdx.x * 256 + tid) * 4;
  float4 s = {0.f, 0.f, 0.f, 0.f};
#pragma unroll
  for (int o = 0; o < 8; ++o) {
    float4 q = *(const float4*)(PA + (size_t)o * 262144 + i);
    s.x += q.x; s.y += q.y; s.z += q.z; s.w += q.w;
  }
  float4 xv = *(const float4*)(x + i);
  float4 v = {xv.x - s.x, xv.y - s.y, xv.z - s.z, xv.w - s.w};
  *(float4*)(v0out + i) = v;
  float g = v.x * v.x + v.y * v.y + v.z * v.z + v.w * v.w;
#pragma unroll
  for (int d = 32; d; d >>= 1) g += __shfl_down(g, d, 64);
  if ((tid & 63) == 0) ws[tid >> 6] = g;
  __syncthreads();
  if (tid == 0) Gam[blockIdx.x] = ws[0] + ws[1] + ws[2] + ws[3];
}

// ---- k_finalize_p: partial conv3x3(d0*v0, flip(Wfb)) over 16-ci quarter ----
// grid 512 = b(4)|coQ(32)|ciQ(4). Gam[256] reduced here. Writes Fp partials.
__global__ __launch_bounds__(256, 2) void k_finalize_p(const float* __restrict__ V,
                                                       const float* __restrict__ Gam,
                                                       const float* __restrict__ Wfb,
                                                       float* __restrict__ Fp) {
  __shared__ float ws[4];
  int tid = threadIdx.x, blk = blockIdx.x;
  int b = blk >> 7, coQ = (blk >> 2) & 31, ciQ = blk & 3;
  int wv = __builtin_amdgcn_readfirstlane(tid >> 6);
  int co = coQ * 4 + wv;                      // 0..127
  int strip4 = ((tid >> 3) & 7) * 4;
  int cg4 = (tid & 7) * 4;
  bool cg0 = (tid & 7) == 0, cg7 = (tid & 7) == 7;
  // reduce Gam[0..255] -> g00 (deterministic, no atomic, no pre-zero)
  float g = Gam[tid];
#pragma unroll
  for (int d = 32; d; d >>= 1) g += __shfl_down(g, d, 64);
  if ((tid & 63) == 0) ws[tid >> 6] = g;
  __syncthreads();
  float d0 = ((float)NUM_ITERS * LR_F) *
             __builtin_amdgcn_rsqf(ws[0] + ws[1] + ws[2] + ws[3]);
  const float* pb = V + (size_t)(b * 64 + ciQ * 16) * 1024;
  float wA[12], wB[12];
  float acc[16], dummy[16];
#pragma unroll
  for (int i = 0; i < 16; ++i) acc[i] = 0.f;
  wldZ(Wfb, co, ciQ * 16, wA);
  for (int ci = 0; ci < 16; ci += 2) {
    wldZ(Wfb, co, ciQ * 16 + ci + 1, wB);
    conv16_reg<false, true>(pb + (size_t)ci * 1024, wA, d0, strip4, cg4, cg0, cg7, acc, dummy);
    if (ci + 2 < 16) wldZ(Wfb, co, ciQ * 16 + ci + 2, wA);
    conv16_reg<false, true>(pb + (size_t)(ci + 1) * 1024, wB, d0, strip4, cg4, cg0, cg7, acc, dummy);
  }
  size_t off = (size_t)ciQ * 524288 + (size_t)(b * 128 + co) * 1024 + strip4 * 32 + cg4;
#pragma unroll
  for (int k = 0; k < 4; ++k) {
    float4 o = {acc[k * 4], acc[k * 4 + 1], acc[k * 4 + 2], acc[k * 4 + 3]};
    *(float4*)(Fp + off + k * 32) = o;
  }
}

// ---- k_fsum2: out += sum4 Fp (base written by k_ysum) -----------------------
__global__ __launch_bounds__(256) void k_fsum2(const float* __restrict__ Fp,
                                               float* __restrict__ out) {
  size_t i = (size_t)(blockIdx.x * 256 + threadIdx.x) * 4;
  float4 s = *(const float4*)(out + i);
#pragma unroll
  for (int q = 0; q < 4; ++q) {
    float4 p = *(const float4*)(Fp + (size_t)q * 524288 + i);
    s.x += p.x; s.y += p.y; s.z += p.z; s.w += p.w;
  }
  *(float4*)(out + i) = s;
}

// ---- launch -----------------------------------------------------------------
extern "C" void kernel_launch(void* const* d_in, const int* in_sizes, int n_in,
                              void* d_out, int out_size, void* d_ws, size_t ws_size,
                              hipStream_t stream) {
  const float* x   = (const float*)d_in[0];
  const float* Wff = (const float*)d_in[1];
  const float* Wfb = (const float*)d_in[2];
  const float* Wb  = (const float*)d_in[3];
  float* out = (float*)d_out;

  float* V    = (float*)d_ws;                  // 262144 (v0)
  float* Gam  = V + VPLANE;                    // 256 block partials
  float* PA   = Gam + 256;                     // 8 * 262144
  float* Q    = PA + (size_t)8 * 262144;       // 4 * 524288
  float* Bq   = Q + (size_t)4 * 524288;        // 4 * 524288
  float* Fp   = Bq + (size_t)4 * 524288;       // 4 * 524288
  float* Y    = Fp + (size_t)4 * 524288;       // 524288 (relu(sum Q))

  hipLaunchKernelGGL(k_init_p,     dim3(512), dim3(256), 0, stream, x, Wff, Wb, Q, Bq);
  hipLaunchKernelGGL(k_ysum,       dim3(512), dim3(256), 0, stream, Q, Bq, Y, out);
  hipLaunchKernelGGL(k_forward_p,  dim3(512), dim3(256), 0, stream, Y, Wfb, PA);
  hipLaunchKernelGGL(k_vnorm,      dim3(256), dim3(256), 0, stream, x, PA, V, Gam);
  hipLaunchKernelGGL(k_finalize_p, dim3(512), dim3(256), 0, stream, V, Gam, Wfb, Fp);
  hipLaunchKernelGGL(k_fsum2,      dim3(512), dim3(256), 0, stream, Fp, out);
}